// Round 10
// baseline (244.020 us; speedup 1.0000x reference)
//
#include <hip/hip_runtime.h>
#include <hip/hip_bf16.h>

using bf16 = __hip_bfloat16;
typedef __attribute__((ext_vector_type(8))) short bf16x8;   // 8 bf16 = 4 VGPRs (MFMA A/B frag)
typedef __attribute__((ext_vector_type(4))) float f32x4;    // MFMA C/D frag

#define DEV __device__ __forceinline__

DEV float exp2fast(float x) { return __builtin_amdgcn_exp2f(x); }  // v_exp_f32 (2^x)

DEV void gload_lds16(const void* g, void* l) {
  __builtin_amdgcn_global_load_lds((const __attribute__((address_space(1))) void*)g,
                                   (__attribute__((address_space(3))) void*)l, 16, 0, 0);
}

DEV unsigned pk2(float lo, float hi) {   // pack 2 f32 -> 2 bf16
  union { bf16 h[2]; unsigned u; } z;
  z.h[0] = __float2bfloat16(lo);
  z.h[1] = __float2bfloat16(hi);
  return z.u;
}

// ---------------------------------------------------------------- prep: 3x cvt + 4x wtrans fused
struct PrepArgs {
  const float* x[3]; bf16* y[3];
  const float* W[4]; bf16* WT[4];
};

__global__ __launch_bounds__(256) void prep_kernel(PrepArgs a) {
  __shared__ float tile[32][33];
  const int b = blockIdx.x;
  if (b < 6144) {
    const int which = b >> 11, blk = b & 2047;
    const int i = blk * 256 + threadIdx.x;
    const float4* xv = (const float4*)a.x[which];
    float4 p = xv[i * 2];
    float4 q = xv[i * 2 + 1];
    union { bf16 h[8]; uint4 v; } u;
    u.h[0] = __float2bfloat16(p.x); u.h[1] = __float2bfloat16(p.y);
    u.h[2] = __float2bfloat16(p.z); u.h[3] = __float2bfloat16(p.w);
    u.h[4] = __float2bfloat16(q.x); u.h[5] = __float2bfloat16(q.y);
    u.h[6] = __float2bfloat16(q.z); u.h[7] = __float2bfloat16(q.w);
    *(uint4*)&a.y[which][(size_t)i * 8] = u.v;
  } else {
    const int w = (b - 6144) >> 10, blk = (b - 6144) & 1023;
    const float* W = a.W[w];
    bf16* WT = a.WT[w];
    const int tx = threadIdx.x & 31, ty = threadIdx.x >> 5;
    const int n0 = (blk & 31) * 32, k0 = (blk >> 5) * 32;
#pragma unroll
    for (int i = ty; i < 32; i += 8)
      tile[i][tx] = W[(size_t)(k0 + i) * 1024 + n0 + tx];
    __syncthreads();
#pragma unroll
    for (int i = ty; i < 32; i += 8)
      WT[(size_t)(n0 + i) * 1024 + k0 + tx] = __float2bfloat16(tile[tx][i]);
  }
}

// v (projected, bf16 [4096][1024]) -> VT [bh=32][dh=64][S=2048]
__global__ __launch_bounds__(256) void vtrans_kernel(const bf16* __restrict__ v,
                                                     bf16* __restrict__ VT) {
  __shared__ bf16 tile[64 * 64];
  const int t = threadIdx.x;
  const int bh = blockIdx.y, b = bh >> 4, h = bh & 15;
  const int s0 = blockIdx.x * 64;
  const int r0 = t >> 3, c8 = t & 7;
#pragma unroll
  for (int it = 0; it < 2; ++it) {
    int r = it * 32 + r0;
    uint4 d = *(const uint4*)&v[(size_t)(b * 2048 + s0 + r) * 1024 + h * 64 + c8 * 8];
    *(uint4*)&tile[r * 64 + ((c8 ^ (r >> 3)) * 8)] = d;
  }
  __syncthreads();
#pragma unroll
  for (int it = 0; it < 2; ++it) {
    int d = it * 32 + r0;
    int sc = c8 * 8;
    union { bf16 h[8]; uint4 v4; } u;
#pragma unroll
    for (int j = 0; j < 8; ++j) {
      int row = sc + j;
      u.h[j] = tile[row * 64 + (((d >> 3) ^ (row >> 3)) * 8) + (d & 7)];
    }
    *(uint4*)&VT[((size_t)bh * 64 + d) * 2048 + s0 + sc] = u.v4;
  }
}

// ---------------------------------------------------------------- GEMM BMx128, BK=32, 2-phase dbuf
template <int BM, typename OutT>
DEV void gemm_core(const bf16* __restrict__ A, const bf16* __restrict__ BT,
                   const float* __restrict__ bias, OutT* __restrict__ out) {
  constexpr int K = 1024, N = 1024;
  constexpr int MI = BM / 32;           // A-frags per wave
  __shared__ bf16 ldsA[2][BM * 32];
  __shared__ bf16 ldsB[2][128 * 32];
  const int t = threadIdx.x;
  const int lane = t & 63, wid = t >> 6;
  const int wr = wid >> 1, wc = wid & 1;
  const int fr = lane & 15, fko = (lane >> 4) * 8;
  const size_t mBase = (size_t)blockIdx.y * BM;
  const size_t nBase = (size_t)blockIdx.x * 128;

  const int srow = t >> 2;              // 0..63
  const int scol = (t & 3) * 8;
  const bf16* gA = A + (mBase + srow) * K + scol;
  const bf16* gB = BT + (nBase + srow) * K + scol;
  const int ldst = wid * 512;           // wave-uniform LDS dest offset

  f32x4 acc[MI][4];
#pragma unroll
  for (int i = 0; i < MI; ++i)
#pragma unroll
    for (int j = 0; j < 4; ++j) acc[i][j] = (f32x4){0.f, 0.f, 0.f, 0.f};

  gload_lds16(gA, &ldsA[0][ldst]);
  if constexpr (BM == 128) gload_lds16(gA + 64 * K, &ldsA[0][ldst + 2048]);
  gload_lds16(gB, &ldsB[0][ldst]);
  gload_lds16(gB + 64 * K, &ldsB[0][ldst + 2048]);
  __syncthreads();

  int buf = 0;
  for (int k0 = 0; k0 < K; k0 += 32) {
    if (k0 + 32 < K) {
      const int kn = k0 + 32;
      gload_lds16(gA + kn, &ldsA[buf ^ 1][ldst]);
      if constexpr (BM == 128) gload_lds16(gA + 64 * K + kn, &ldsA[buf ^ 1][ldst + 2048]);
      gload_lds16(gB + kn, &ldsB[buf ^ 1][ldst]);
      gload_lds16(gB + 64 * K + kn, &ldsB[buf ^ 1][ldst + 2048]);
    }
    bf16x8 aF[MI], bF[4];
#pragma unroll
    for (int i = 0; i < MI; ++i)
      aF[i] = *(const bf16x8*)&ldsA[buf][(wr * (BM / 2) + i * 16 + fr) * 32 + fko];
#pragma unroll
    for (int j = 0; j < 4; ++j)
      bF[j] = *(const bf16x8*)&ldsB[buf][(wc * 64 + j * 16 + fr) * 32 + fko];
#pragma unroll
    for (int i = 0; i < MI; ++i)
#pragma unroll
      for (int j = 0; j < 4; ++j)
        acc[i][j] = __builtin_amdgcn_mfma_f32_16x16x32_bf16(aF[i], bF[j], acc[i][j], 0, 0, 0);
    __syncthreads();
    buf ^= 1;
  }

  const int orow = (int)mBase + wr * (BM / 2) + (lane >> 4) * 4;
  const int ocol = (int)nBase + wc * 64 + fr;
#pragma unroll
  for (int j = 0; j < 4; ++j) {
    const float bj = bias[ocol + j * 16];
#pragma unroll
    for (int i = 0; i < MI; ++i)
#pragma unroll
      for (int r = 0; r < 4; ++r) {
        float v = fmaxf(acc[i][j][r] + bj, 0.f);
        size_t idx = (size_t)(orow + i * 16 + r) * N + (ocol + j * 16);
        if constexpr (sizeof(OutT) == 2) out[idx] = __float2bfloat16(v);
        else out[idx] = v;
      }
  }
}

struct QKVArgs {
  const bf16* A[3];
  const bf16* BT[3];
  const float* bias[3];
  bf16* out[3];
};

__global__ __launch_bounds__(256) void gemm_qkv_kernel(QKVArgs args) {
  const int z = blockIdx.z;
  gemm_core<128, bf16>(args.A[z], args.BT[z], args.bias[z], args.out[z]);
}

__global__ __launch_bounds__(256) void gemm_out_kernel(const bf16* __restrict__ A,
                                                       const bf16* __restrict__ BT,
                                                       const float* __restrict__ bias,
                                                       float* __restrict__ out) {
  gemm_core<64, float>(A, BT, bias, out);   // 64x128 tiles -> 512 blocks = 2/CU
}

// ---------------------------------------------------------------- flash attention, KV-SPLIT
// Chunks: qt<16 -> 1 chunk (tiles 0..qt, writes final O). qt>=16 -> 2 chunks:
// c0 = tiles [0,16), c1 = tiles [16, qt+1) (diag); both write partial O^T(bf16)+m,l.
// cidx map (LPT: big chunks first): 0..15 -> (qt=16+cidx, c=0); 16..31 -> (qt=47-cidx, c=1);
// 32..47 -> (qt=47-cidx, c=0). Grid 48x32 = 1536 blocks; 32KB LDS -> 5 blocks/CU.
__global__ __launch_bounds__(256, 4) void attn_kernel(const bf16* __restrict__ Qb,
                                                      const bf16* __restrict__ Kb,
                                                      const bf16* __restrict__ VTb,
                                                      bf16* __restrict__ Ob,
                                                      bf16* __restrict__ pO,
                                                      float* __restrict__ pm,
                                                      float* __restrict__ pl) {
  constexpr int Dm = 1024, S = 2048;
  __shared__ bf16 ldsK[2][4096];   // KVBLK=64: [kv64][d64] per buf, 16KB
  __shared__ bf16 ldsV[2][4096];   // [d64][kv64] per buf, 16KB
  const int t = threadIdx.x, l = t & 63, wid = t >> 6;

  // XCD swizzle (bijective: 1536 = 8*192; each XCD = 4 bh, cidx ascending = LPT)
  const int lin = blockIdx.y * 48 + blockIdx.x;
  const int swz = (lin & 7) * 192 + (lin >> 3);
  const int bh = swz / 48, cidx = swz % 48;
  int qt, c0;
  if (cidx < 16)      { qt = 16 + cidx;        c0 = 0; }
  else if (cidx < 32) { qt = 31 - (cidx - 16); c0 = 1; }
  else                { qt = 47 - cidx;        c0 = 0; }
  const int t0 = c0 * 16;
  const int t1 = (c0 == 0 && qt >= 16) ? 16 : (qt + 1);
  const bool two_chunk = (qt >= 16);

  const int b = bh >> 4, h = bh & 15;
  const int q4 = l & 15, fg = l >> 4;
  const int qw = qt * 64 + wid * 16;
  const bf16* Qg = Qb + (size_t)b * S * Dm + h * 64;
  const bf16* Kg = Kb + (size_t)b * S * Dm + h * 64;
  const bf16* VTg = VTb + (size_t)bh * 64 * S;

  // staging: lane covers (row = base + l>>3 (+8), chunk = (l&7)^(row&7))
  const int srow = l >> 3;
  const int schunk = (l & 7) ^ srow;
  const bf16* kSrc = Kg + (size_t)(wid * 16 + srow) * Dm + schunk * 8;
  const bf16* vSrc = VTg + (size_t)(wid * 16 + srow) * S + schunk * 8;

  const int idx0 = ((q4 + ((l & 16) ? 32 : 0)) << 2);
  const int idx1 = idx0 + 64;
  constexpr float SC = 0.18033688f;   // 0.125 * log2(e)

  bf16x8 qF[2];
#pragma unroll
  for (int kd = 0; kd < 2; ++kd)
    qF[kd] = *(const bf16x8*)&Qg[(size_t)(qw + q4) * Dm + kd * 32 + fg * 8];

  f32x4 oacc[4];
#pragma unroll
  for (int n = 0; n < 4; ++n) oacc[n] = (f32x4){0.f, 0.f, 0.f, 0.f};
  float mrow = -3.0e38f, lsum = 0.f;

  auto STAGE = [&](int tile, int bi) {
    const size_t kvb = (size_t)tile * 64;
    gload_lds16(kSrc + kvb * Dm, &ldsK[bi][wid * 1024]);
    gload_lds16(kSrc + (kvb + 8) * Dm, &ldsK[bi][wid * 1024 + 512]);
    gload_lds16(vSrc + kvb, &ldsV[bi][wid * 1024]);
    gload_lds16(vSrc + kvb + 8 * S, &ldsV[bi][wid * 1024 + 512]);
  };

  STAGE(t0, 0);
  __syncthreads();

  int buf = 0;
  for (int tile = t0; tile < t1; ++tile) {
    if (tile + 1 < t1) STAGE(tile + 1, buf ^ 1);
    const bf16* kb = &ldsK[buf][0];
    const bf16* vb = &ldsV[buf][0];

    // S^T = K Q^T : D[kv][q], col = q4
    f32x4 sT[4];
#pragma unroll
    for (int n = 0; n < 4; ++n) sT[n] = (f32x4){0.f, 0.f, 0.f, 0.f};
    __builtin_amdgcn_s_setprio(1);
#pragma unroll
    for (int n = 0; n < 4; ++n) {
#pragma unroll
      for (int kd = 0; kd < 2; ++kd) {
        bf16x8 kf = *(const bf16x8*)&kb[(n * 16 + q4) * 64 + (((kd * 4 + fg) ^ (q4 & 7)) * 8)];
        sT[n] = __builtin_amdgcn_mfma_f32_16x16x32_bf16(kf, qF[kd], sT[n], 0, 0, 0);
      }
    }
    __builtin_amdgcn_s_setprio(0);

    // scale into exp2 domain + causal mask (only the diagonal tile)
    const bool needmask = (tile == qt);
    const int kvb = tile * 64, qrow = qw + q4;
#pragma unroll
    for (int n = 0; n < 4; ++n)
#pragma unroll
      for (int r = 0; r < 4; ++r) {
        float vv = sT[n][r] * SC;
        if (needmask) {
          int kv = kvb + n * 16 + fg * 4 + r;
          if (kv > qrow) vv = -1e30f;
        }
        sT[n][r] = vv;
      }
    // row max: in-lane tree + 2 shfl
    float vm[4];
#pragma unroll
    for (int n = 0; n < 4; ++n)
      vm[n] = fmaxf(fmaxf(sT[n][0], sT[n][1]), fmaxf(sT[n][2], sT[n][3]));
    float tmax = fmaxf(fmaxf(vm[0], vm[1]), fmaxf(vm[2], vm[3]));
    tmax = fmaxf(tmax, __shfl_xor(tmax, 16, 64));
    tmax = fmaxf(tmax, __shfl_xor(tmax, 32, 64));
    if (__any(tmax > mrow + 8.f)) {      // defer-max
      const float mnew = fmaxf(mrow, tmax);
      const float corr = exp2fast(mrow - mnew);
      mrow = mnew;
      lsum *= corr;
#pragma unroll
      for (int n = 0; n < 4; ++n)
#pragma unroll
        for (int r = 0; r < 4; ++r) oacc[n][r] *= corr;
    }
    float rv[4];
#pragma unroll
    for (int n = 0; n < 4; ++n) {
#pragma unroll
      for (int r = 0; r < 4; ++r) sT[n][r] = exp2fast(sT[n][r] - mrow);
      rv[n] = (sT[n][0] + sT[n][1]) + (sT[n][2] + sT[n][3]);
    }
    float rs = (rv[0] + rv[1]) + (rv[2] + rv[3]);
    rs += __shfl_xor(rs, 16, 64);
    rs += __shfl_xor(rs, 32, 64);
    lsum += rs;

    // PV: O^T += V^T P^T (P^T B-frags built in-register via pk2 + bpermute)
#pragma unroll
    for (int ks = 0; ks < 2; ++ks) {
      const unsigned X0 = pk2(sT[2 * ks][0], sT[2 * ks][1]);
      const unsigned X1 = pk2(sT[2 * ks][2], sT[2 * ks][3]);
      const unsigned Y0 = pk2(sT[2 * ks + 1][0], sT[2 * ks + 1][1]);
      const unsigned Y1 = pk2(sT[2 * ks + 1][2], sT[2 * ks + 1][3]);
      union { int u[4]; bf16x8 v; } bfr;
      int zx, zy;
      zx = __builtin_amdgcn_ds_bpermute(idx0, (int)X0);
      zy = __builtin_amdgcn_ds_bpermute(idx0, (int)Y0);
      bfr.u[0] = (l & 32) ? zy : zx;
      zx = __builtin_amdgcn_ds_bpermute(idx0, (int)X1);
      zy = __builtin_amdgcn_ds_bpermute(idx0, (int)Y1);
      bfr.u[1] = (l & 32) ? zy : zx;
      zx = __builtin_amdgcn_ds_bpermute(idx1, (int)X0);
      zy = __builtin_amdgcn_ds_bpermute(idx1, (int)Y0);
      bfr.u[2] = (l & 32) ? zy : zx;
      zx = __builtin_amdgcn_ds_bpermute(idx1, (int)X1);
      zy = __builtin_amdgcn_ds_bpermute(idx1, (int)Y1);
      bfr.u[3] = (l & 32) ? zy : zx;
      __builtin_amdgcn_s_setprio(1);
#pragma unroll
      for (int dblk = 0; dblk < 4; ++dblk) {
        bf16x8 vf = *(const bf16x8*)&vb[(dblk * 16 + q4) * 64 + (((ks * 4 + fg) ^ (q4 & 7)) * 8)];
        oacc[dblk] = __builtin_amdgcn_mfma_f32_16x16x32_bf16(vf, bfr.v, oacc[dblk], 0, 0, 0);
      }
      __builtin_amdgcn_s_setprio(0);
    }
    __syncthreads();
    buf ^= 1;
  }

  // epilogue: per-wave LDS transpose (raw for partials, normalized for final)
  bf16* ldsT = &ldsK[0][0] + wid * 1152;   // 16 rows x 72 (pad); fits in ldsK[2][4096]
  const float sc = two_chunk ? 1.f : (1.f / lsum);
#pragma unroll
  for (int dblk = 0; dblk < 4; ++dblk)
#pragma unroll
    for (int r = 0; r < 4; ++r) {
      int d = dblk * 16 + fg * 4 + r;
      ldsT[q4 * 72 + d] = __float2bfloat16(oacc[dblk][r] * sc);
    }
  asm volatile("s_waitcnt lgkmcnt(0)" ::: "memory");
  __builtin_amdgcn_sched_barrier(0);
  const int rq = l >> 2, dq = (l & 3) * 16;
  if (two_chunk) {
    const int slot = (bh * 16 + (qt - 16)) * 2 + c0;
    bf16* pb = pO + (size_t)slot * 4096;
#pragma unroll
    for (int i = 0; i < 2; ++i) {
      uint4 w = *(const uint4*)&ldsT[rq * 72 + dq + 8 * i];
      *(uint4*)&pb[(wid * 16 + rq) * 64 + dq + 8 * i] = w;
    }
    if (l < 16) {
      pm[slot * 64 + wid * 16 + l] = mrow;
      pl[slot * 64 + wid * 16 + l] = lsum;
    }
  } else {
#pragma unroll
    for (int i = 0; i < 2; ++i) {
      uint4 w = *(const uint4*)&ldsT[rq * 72 + dq + 8 * i];
      *(uint4*)&Ob[((size_t)b * S + qw + rq) * Dm + h * 64 + dq + 8 * i] = w;
    }
  }
}

// ---------------------------------------------------------------- combine: merge 2 partials (qt>=16)
__global__ __launch_bounds__(256) void combine_kernel(const bf16* __restrict__ pO,
                                                      const float* __restrict__ pm,
                                                      const float* __restrict__ pl,
                                                      bf16* __restrict__ Ob) {
  constexpr int Dm = 1024, S = 2048;
  const int qt = 16 + blockIdx.x, bh = blockIdx.y;
  const int b = bh >> 4, h = bh & 15;
  const int t = threadIdx.x;
  const int row = t >> 2, dg = (t & 3) * 16;
  const int slot0 = (bh * 16 + (qt - 16)) * 2;
  const float m0 = pm[slot0 * 64 + row], m1 = pm[(slot0 + 1) * 64 + row];
  const float l0 = pl[slot0 * 64 + row], l1 = pl[(slot0 + 1) * 64 + row];
  const float M = fmaxf(m0, m1);
  const float w0 = exp2fast(m0 - M), w1 = exp2fast(m1 - M);
  const float L = w0 * l0 + w1 * l1;
  const float s0 = w0 / L, s1 = w1 / L;
  const bf16* p0 = pO + (size_t)slot0 * 4096 + row * 64 + dg;
  const bf16* p1 = p0 + 4096;
  bf16* dst = Ob + ((size_t)b * S + qt * 64 + row) * Dm + h * 64 + dg;
#pragma unroll
  for (int i = 0; i < 2; ++i) {
    union { bf16 h8[8]; uint4 v; } a0, a1, o;
    a0.v = *(const uint4*)&p0[8 * i];
    a1.v = *(const uint4*)&p1[8 * i];
#pragma unroll
    for (int j = 0; j < 8; ++j)
      o.h8[j] = __float2bfloat16(s0 * __bfloat162float(a0.h8[j]) +
                                 s1 * __bfloat162float(a1.h8[j]));
    *(uint4*)&dst[8 * i] = o.v;
  }
}

// ---------------------------------------------------------------- launch
extern "C" void kernel_launch(void* const* d_in, const int* in_sizes, int n_in,
                              void* d_out, int out_size, void* d_ws, size_t ws_size,
                              hipStream_t stream) {
  const float* query = (const float*)d_in[0];
  const float* key   = (const float*)d_in[1];
  const float* value = (const float*)d_in[2];
  const float* Wq = (const float*)d_in[3]; const float* bq = (const float*)d_in[4];
  const float* Wk = (const float*)d_in[5]; const float* bk = (const float*)d_in[6];
  const float* Wv = (const float*)d_in[7]; const float* bv = (const float*)d_in[8];
  const float* Wo = (const float*)d_in[9]; const float* bo = (const float*)d_in[10];
  float* out = (float*)d_out;

  char* ws = (char*)d_ws;
  const size_t MB = 1024 * 1024;
  // S0 0-8: xq -> VT | S1 8-16: xk -> pO | S2 16-24: xv -> pm/pl
  // S3 24-32: qp | S4 32-40: kp | S5 40-48: vp -> attnO | S6 48-56: weights
  bf16* xq  = (bf16*)(ws + 0 * MB);
  bf16* xk  = (bf16*)(ws + 8 * MB);
  bf16* xv  = (bf16*)(ws + 16 * MB);
  bf16* qp  = (bf16*)(ws + 24 * MB);
  bf16* kp  = (bf16*)(ws + 32 * MB);
  bf16* vp  = (bf16*)(ws + 40 * MB);
  bf16* WqT = (bf16*)(ws + 48 * MB);
  bf16* WkT = (bf16*)(ws + 50 * MB);
  bf16* WvT = (bf16*)(ws + 52 * MB);
  bf16* WoT = (bf16*)(ws + 54 * MB);
  bf16*  VT    = xq;                       // xq dead after gemm_qkv
  bf16*  pO    = xk;                       // xk dead after gemm_qkv (8MB = 1024 slots x 8KB)
  float* pm    = (float*)(ws + 16 * MB);   // xv dead after gemm_qkv (256KB)
  float* pl    = (float*)(ws + 17 * MB);   // (256KB)
  bf16*  attnO = vp;                       // vp dead after vtrans

  PrepArgs pa;
  pa.x[0] = query; pa.x[1] = key; pa.x[2] = value;
  pa.y[0] = xq; pa.y[1] = xk; pa.y[2] = xv;
  pa.W[0] = Wq; pa.W[1] = Wk; pa.W[2] = Wv; pa.W[3] = Wo;
  pa.WT[0] = WqT; pa.WT[1] = WkT; pa.WT[2] = WvT; pa.WT[3] = WoT;
  prep_kernel<<<10240, 256, 0, stream>>>(pa);

  QKVArgs qa;
  qa.A[0] = xq;  qa.A[1] = xk;  qa.A[2] = xv;
  qa.BT[0] = WqT; qa.BT[1] = WkT; qa.BT[2] = WvT;
  qa.bias[0] = bq; qa.bias[1] = bk; qa.bias[2] = bv;
  qa.out[0] = qp; qa.out[1] = kp; qa.out[2] = vp;
  gemm_qkv_kernel<<<dim3(8, 32, 3), 256, 0, stream>>>(qa);

  vtrans_kernel<<<dim3(32, 32), 256, 0, stream>>>(vp, VT);
  attn_kernel<<<dim3(48, 32), 256, 0, stream>>>(qp, kp, VT, attnO, pO, pm, pl);
  combine_kernel<<<dim3(16, 32), 256, 0, stream>>>(pO, pm, pl, attnO);
  gemm_out_kernel<<<dim3(8, 64), 256, 0, stream>>>(attnO, WoT, bo, out);
}

// Round 11
// 233.264 us; speedup vs baseline: 1.0461x; 1.0461x over previous
//
#include <hip/hip_runtime.h>
#include <hip/hip_bf16.h>

using bf16 = __hip_bfloat16;
typedef __attribute__((ext_vector_type(8))) short bf16x8;   // 8 bf16 = 4 VGPRs (MFMA A/B frag)
typedef __attribute__((ext_vector_type(4))) float f32x4;    // MFMA C/D frag

#define DEV __device__ __forceinline__

DEV float exp2fast(float x) { return __builtin_amdgcn_exp2f(x); }  // v_exp_f32 (2^x)

DEV void gload_lds16(const void* g, void* l) {
  __builtin_amdgcn_global_load_lds((const __attribute__((address_space(1))) void*)g,
                                   (__attribute__((address_space(3))) void*)l, 16, 0, 0);
}

DEV unsigned pk2(float lo, float hi) {   // pack 2 f32 -> 2 bf16
  union { bf16 h[2]; unsigned u; } z;
  z.h[0] = __float2bfloat16(lo);
  z.h[1] = __float2bfloat16(hi);
  return z.u;
}

// ---------------------------------------------------------------- prep: 3x cvt + 4x wtrans fused
struct PrepArgs {
  const float* x[3]; bf16* y[3];
  const float* W[4]; bf16* WT[4];
};

__global__ __launch_bounds__(256) void prep_kernel(PrepArgs a) {
  __shared__ float tile[32][33];
  const int b = blockIdx.x;
  if (b < 6144) {
    const int which = b >> 11, blk = b & 2047;
    const int i = blk * 256 + threadIdx.x;
    const float4* xv = (const float4*)a.x[which];
    float4 p = xv[i * 2];
    float4 q = xv[i * 2 + 1];
    union { bf16 h[8]; uint4 v; } u;
    u.h[0] = __float2bfloat16(p.x); u.h[1] = __float2bfloat16(p.y);
    u.h[2] = __float2bfloat16(p.z); u.h[3] = __float2bfloat16(p.w);
    u.h[4] = __float2bfloat16(q.x); u.h[5] = __float2bfloat16(q.y);
    u.h[6] = __float2bfloat16(q.z); u.h[7] = __float2bfloat16(q.w);
    *(uint4*)&a.y[which][(size_t)i * 8] = u.v;
  } else {
    const int w = (b - 6144) >> 10, blk = (b - 6144) & 1023;
    const float* W = a.W[w];
    bf16* WT = a.WT[w];
    const int tx = threadIdx.x & 31, ty = threadIdx.x >> 5;
    const int n0 = (blk & 31) * 32, k0 = (blk >> 5) * 32;
#pragma unroll
    for (int i = ty; i < 32; i += 8)
      tile[i][tx] = W[(size_t)(k0 + i) * 1024 + n0 + tx];
    __syncthreads();
#pragma unroll
    for (int i = ty; i < 32; i += 8)
      WT[(size_t)(n0 + i) * 1024 + k0 + tx] = __float2bfloat16(tile[tx][i]);
  }
}

// v (projected, bf16 [4096][1024]) -> VT [bh=32][dh=64][S=2048]
__global__ __launch_bounds__(256) void vtrans_kernel(const bf16* __restrict__ v,
                                                     bf16* __restrict__ VT) {
  __shared__ bf16 tile[64 * 64];
  const int t = threadIdx.x;
  const int bh = blockIdx.y, b = bh >> 4, h = bh & 15;
  const int s0 = blockIdx.x * 64;
  const int r0 = t >> 3, c8 = t & 7;
#pragma unroll
  for (int it = 0; it < 2; ++it) {
    int r = it * 32 + r0;
    uint4 d = *(const uint4*)&v[(size_t)(b * 2048 + s0 + r) * 1024 + h * 64 + c8 * 8];
    *(uint4*)&tile[r * 64 + ((c8 ^ (r >> 3)) * 8)] = d;
  }
  __syncthreads();
#pragma unroll
  for (int it = 0; it < 2; ++it) {
    int d = it * 32 + r0;
    int sc = c8 * 8;
    union { bf16 h[8]; uint4 v4; } u;
#pragma unroll
    for (int j = 0; j < 8; ++j) {
      int row = sc + j;
      u.h[j] = tile[row * 64 + (((d >> 3) ^ (row >> 3)) * 8) + (d & 7)];
    }
    *(uint4*)&VT[((size_t)bh * 64 + d) * 2048 + s0 + sc] = u.v4;
  }
}

// ---------------------------------------------------------------- GEMM BMx128, BK=32, 2-phase dbuf
// __launch_bounds__(256,4): force 4 waves/EU (= 4 blocks/CU), cap VGPR at 128.
template <int BM, typename OutT>
DEV void gemm_core(const bf16* __restrict__ A, const bf16* __restrict__ BT,
                   const float* __restrict__ bias, OutT* __restrict__ out) {
  constexpr int K = 1024, N = 1024;
  constexpr int MI = BM / 32;           // A-frags per wave
  __shared__ bf16 ldsA[2][BM * 32];
  __shared__ bf16 ldsB[2][128 * 32];
  const int t = threadIdx.x;
  const int lane = t & 63, wid = t >> 6;
  const int wr = wid >> 1, wc = wid & 1;
  const int fr = lane & 15, fko = (lane >> 4) * 8;
  const size_t mBase = (size_t)blockIdx.y * BM;
  const size_t nBase = (size_t)blockIdx.x * 128;

  const int srow = t >> 2;              // 0..63
  const int scol = (t & 3) * 8;
  const bf16* gA = A + (mBase + srow) * K + scol;
  const bf16* gB = BT + (nBase + srow) * K + scol;
  const int ldst = wid * 512;           // wave-uniform LDS dest offset

  f32x4 acc[MI][4];
#pragma unroll
  for (int i = 0; i < MI; ++i)
#pragma unroll
    for (int j = 0; j < 4; ++j) acc[i][j] = (f32x4){0.f, 0.f, 0.f, 0.f};

  gload_lds16(gA, &ldsA[0][ldst]);
  if constexpr (BM == 128) gload_lds16(gA + 64 * K, &ldsA[0][ldst + 2048]);
  gload_lds16(gB, &ldsB[0][ldst]);
  gload_lds16(gB + 64 * K, &ldsB[0][ldst + 2048]);
  __syncthreads();

  int buf = 0;
  for (int k0 = 0; k0 < K; k0 += 32) {
    if (k0 + 32 < K) {
      const int kn = k0 + 32;
      gload_lds16(gA + kn, &ldsA[buf ^ 1][ldst]);
      if constexpr (BM == 128) gload_lds16(gA + 64 * K + kn, &ldsA[buf ^ 1][ldst + 2048]);
      gload_lds16(gB + kn, &ldsB[buf ^ 1][ldst]);
      gload_lds16(gB + 64 * K + kn, &ldsB[buf ^ 1][ldst + 2048]);
    }
    bf16x8 aF[MI], bF[4];
#pragma unroll
    for (int i = 0; i < MI; ++i)
      aF[i] = *(const bf16x8*)&ldsA[buf][(wr * (BM / 2) + i * 16 + fr) * 32 + fko];
#pragma unroll
    for (int j = 0; j < 4; ++j)
      bF[j] = *(const bf16x8*)&ldsB[buf][(wc * 64 + j * 16 + fr) * 32 + fko];
#pragma unroll
    for (int i = 0; i < MI; ++i)
#pragma unroll
      for (int j = 0; j < 4; ++j)
        acc[i][j] = __builtin_amdgcn_mfma_f32_16x16x32_bf16(aF[i], bF[j], acc[i][j], 0, 0, 0);
    __syncthreads();
    buf ^= 1;
  }

  const int orow = (int)mBase + wr * (BM / 2) + (lane >> 4) * 4;
  const int ocol = (int)nBase + wc * 64 + fr;
#pragma unroll
  for (int j = 0; j < 4; ++j) {
    const float bj = bias[ocol + j * 16];
#pragma unroll
    for (int i = 0; i < MI; ++i)
#pragma unroll
      for (int r = 0; r < 4; ++r) {
        float v = fmaxf(acc[i][j][r] + bj, 0.f);
        size_t idx = (size_t)(orow + i * 16 + r) * N + (ocol + j * 16);
        if constexpr (sizeof(OutT) == 2) out[idx] = __float2bfloat16(v);
        else out[idx] = v;
      }
  }
}

struct QKVArgs {
  const bf16* A[3];
  const bf16* BT[3];
  const float* bias[3];
  bf16* out[3];
};

__global__ __launch_bounds__(256, 4) void gemm_qkv_kernel(QKVArgs args) {
  const int z = blockIdx.z;
  gemm_core<128, bf16>(args.A[z], args.BT[z], args.bias[z], args.out[z]);
}

__global__ __launch_bounds__(256, 4) void gemm_out_kernel(const bf16* __restrict__ A,
                                                          const bf16* __restrict__ BT,
                                                          const float* __restrict__ bias,
                                                          float* __restrict__ out) {
  gemm_core<64, float>(A, BT, bias, out);   // 64x128 tiles -> 512 blocks = 2/CU
}

// ---------------------------------------------------------------- flash attention (causal, swapped QK^T, PAIRED)
// R5 structure (measured 58.0us) + exp2-domain softmax + defer-max.
// Block handles q-tiles {p, 31-p} sequentially -> uniform 33 KV tiles/block.
// Grid: 512 blocks (16 pairs x 32 bh) = exactly 2 blocks/CU, zero drain tail.
__global__ __launch_bounds__(256, 4) void attn_kernel(const bf16* __restrict__ Qb,
                                                      const bf16* __restrict__ Kb,
                                                      const bf16* __restrict__ VTb,
                                                      bf16* __restrict__ Ob) {
  constexpr int Dm = 1024, S = 2048;
  __shared__ bf16 ldsKV[16384];   // [K buf0|K buf1|V buf0|V buf1] 4096 each (32KB)
  const int t = threadIdx.x, l = t & 63, wid = t >> 6;

  // XCD chunk swizzle (bijective, 512 = 8*64): each XCD gets 4 bh x 16 pairs
  const int lin = blockIdx.y * 16 + blockIdx.x;
  const int swz = (lin & 7) * 64 + (lin >> 3);
  const int bh = swz >> 4, pairp = swz & 15;
  const int b = bh >> 4, h = bh & 15;
  const int q4 = l & 15, fg = l >> 4;              // lane's q-col, k-group
  const bf16* Qg = Qb + (size_t)b * S * Dm + h * 64;
  const bf16* Kg = Kb + (size_t)b * S * Dm + h * 64;
  const bf16* VTg = VTb + (size_t)bh * 64 * S;

  // staging: lane covers (row = base + l>>3 (+8), chunk = (l&7) ^ (row&7))
  const int srow = l >> 3;
  const int schunk = (l & 7) ^ srow;
  const bf16* kSrc = Kg + (size_t)(wid * 16 + srow) * Dm + schunk * 8;
  const bf16* vSrc = VTg + (size_t)(wid * 16 + srow) * S + schunk * 8;
  bf16* kDst = ldsKV + wid * 1024;                 // + buf*4096
  bf16* vDst = ldsKV + 8192 + wid * 1024;

  // bpermute indices for P^T B-frag build
  const int idx0 = ((q4 + ((l & 16) ? 32 : 0)) << 2);
  const int idx1 = idx0 + 64;
  constexpr float SC = 0.18033688f;   // 0.125 * log2(e)

#pragma unroll 1
  for (int ph = 0; ph < 2; ++ph) {
    const int qt = ph ? (31 - pairp) : pairp;
    const int qb = qt * 64;
    const int qw = qb + wid * 16;                  // this wave's 16 q-rows

    bf16x8 qF[2];
#pragma unroll
    for (int kd = 0; kd < 2; ++kd)
      qF[kd] = *(const bf16x8*)&Qg[(size_t)(qw + q4) * Dm + kd * 32 + fg * 8];

    f32x4 oacc[4];                                 // O^T: [d-block][q] accum
#pragma unroll
    for (int n = 0; n < 4; ++n) oacc[n] = (f32x4){0.f, 0.f, 0.f, 0.f};
    float mrow = -3.0e38f, lsum = 0.f;             // per-lane scalars (one q-row)

    const int nTiles = qt + 1;

    // prologue: stage tile 0 into buf 0
    gload_lds16(kSrc, kDst);
    gload_lds16(kSrc + 8 * Dm, kDst + 512);
    gload_lds16(vSrc, vDst);
    gload_lds16(vSrc + 8 * S, vDst + 512);
    __syncthreads();

    int buf = 0;
    for (int tile = 0; tile < nTiles; ++tile) {
      const int kvb = tile * 64;
      if (tile + 1 < nTiles) {                     // prefetch next tile
        const int nb = kvb + 64;
        gload_lds16(kSrc + (size_t)nb * Dm, kDst + (buf ^ 1) * 4096);
        gload_lds16(kSrc + (size_t)(nb + 8) * Dm, kDst + (buf ^ 1) * 4096 + 512);
        gload_lds16(vSrc + nb, vDst + (buf ^ 1) * 4096);
        gload_lds16(vSrc + nb + 8 * S, vDst + (buf ^ 1) * 4096 + 512);
      }
      const bf16* kb = ldsKV + buf * 4096;
      const bf16* vb = ldsKV + 8192 + buf * 4096;

      // S^T = K Q^T : D[kv][q], col = q4
      f32x4 sT[4];
#pragma unroll
      for (int n = 0; n < 4; ++n) sT[n] = (f32x4){0.f, 0.f, 0.f, 0.f};
      __builtin_amdgcn_s_setprio(1);
#pragma unroll
      for (int n = 0; n < 4; ++n) {
#pragma unroll
        for (int kd = 0; kd < 2; ++kd) {
          bf16x8 kf = *(const bf16x8*)&kb[(n * 16 + q4) * 64 + (((kd * 4 + fg) ^ (q4 & 7)) * 8)];
          sT[n] = __builtin_amdgcn_mfma_f32_16x16x32_bf16(kf, qF[kd], sT[n], 0, 0, 0);
        }
      }
      __builtin_amdgcn_s_setprio(0);
      // scale into exp2 domain + causal mask (only diagonal tile masks)
      const bool needmask = (tile == nTiles - 1);
      const int qrow = qw + q4;
#pragma unroll
      for (int n = 0; n < 4; ++n)
#pragma unroll
        for (int r = 0; r < 4; ++r) {
          float vv = sT[n][r] * SC;
          if (needmask) {
            int kv = kvb + n * 16 + fg * 4 + r;
            if (kv > qrow) vv = -1e30f;
          }
          sT[n][r] = vv;
        }
      // online softmax: in-lane tree + 2 shfl_xor
      float vm[4];
#pragma unroll
      for (int n = 0; n < 4; ++n)
        vm[n] = fmaxf(fmaxf(sT[n][0], sT[n][1]), fmaxf(sT[n][2], sT[n][3]));
      float tmax = fmaxf(fmaxf(vm[0], vm[1]), fmaxf(vm[2], vm[3]));
      tmax = fmaxf(tmax, __shfl_xor(tmax, 16, 64));
      tmax = fmaxf(tmax, __shfl_xor(tmax, 32, 64));
      if (__any(tmax > mrow + 8.f)) {      // defer-max (log2 units)
        const float mnew = fmaxf(mrow, tmax);
        const float corr = exp2fast(mrow - mnew);
        mrow = mnew;
        lsum *= corr;
#pragma unroll
        for (int n = 0; n < 4; ++n)
#pragma unroll
          for (int r = 0; r < 4; ++r) oacc[n][r] *= corr;
      }
      float rv[4];
#pragma unroll
      for (int n = 0; n < 4; ++n) {
#pragma unroll
        for (int r = 0; r < 4; ++r) sT[n][r] = exp2fast(sT[n][r] - mrow);
        rv[n] = (sT[n][0] + sT[n][1]) + (sT[n][2] + sT[n][3]);
      }
      float rs = (rv[0] + rv[1]) + (rv[2] + rv[3]);
      rs += __shfl_xor(rs, 16, 64);
      rs += __shfl_xor(rs, 32, 64);
      lsum += rs;

      // PV: O^T += V^T P^T. Build P^T B-frags in-register.
#pragma unroll
      for (int ks = 0; ks < 2; ++ks) {
        const unsigned X0 = pk2(sT[2 * ks][0], sT[2 * ks][1]);
        const unsigned X1 = pk2(sT[2 * ks][2], sT[2 * ks][3]);
        const unsigned Y0 = pk2(sT[2 * ks + 1][0], sT[2 * ks + 1][1]);
        const unsigned Y1 = pk2(sT[2 * ks + 1][2], sT[2 * ks + 1][3]);
        union { int u[4]; bf16x8 v; } bfr;
        int zx, zy;
        zx = __builtin_amdgcn_ds_bpermute(idx0, (int)X0);
        zy = __builtin_amdgcn_ds_bpermute(idx0, (int)Y0);
        bfr.u[0] = (l & 32) ? zy : zx;
        zx = __builtin_amdgcn_ds_bpermute(idx0, (int)X1);
        zy = __builtin_amdgcn_ds_bpermute(idx0, (int)Y1);
        bfr.u[1] = (l & 32) ? zy : zx;
        zx = __builtin_amdgcn_ds_bpermute(idx1, (int)X0);
        zy = __builtin_amdgcn_ds_bpermute(idx1, (int)Y0);
        bfr.u[2] = (l & 32) ? zy : zx;
        zx = __builtin_amdgcn_ds_bpermute(idx1, (int)X1);
        zy = __builtin_amdgcn_ds_bpermute(idx1, (int)Y1);
        bfr.u[3] = (l & 32) ? zy : zx;
        __builtin_amdgcn_s_setprio(1);
#pragma unroll
        for (int dblk = 0; dblk < 4; ++dblk) {
          bf16x8 vf = *(const bf16x8*)&vb[(dblk * 16 + q4) * 64 + (((ks * 4 + fg) ^ (q4 & 7)) * 8)];
          oacc[dblk] = __builtin_amdgcn_mfma_f32_16x16x32_bf16(vf, bfr.v, oacc[dblk], 0, 0, 0);
        }
        __builtin_amdgcn_s_setprio(0);
      }
      __syncthreads();   // drains prefetch (vmcnt0) + guards buf overwrite
      buf ^= 1;
    }

    // epilogue: per-wave LDS transpose of O^T -> coalesced store
    bf16* ldsT = ldsKV + wid * 1152;               // 16 rows x 72 (pad) bf16
    const float inv = 1.f / lsum;
#pragma unroll
    for (int dblk = 0; dblk < 4; ++dblk)
#pragma unroll
      for (int r = 0; r < 4; ++r) {
        int d = dblk * 16 + fg * 4 + r;
        ldsT[q4 * 72 + d] = __float2bfloat16(oacc[dblk][r] * inv);
      }
    asm volatile("s_waitcnt lgkmcnt(0)" ::: "memory");
    __builtin_amdgcn_sched_barrier(0);
    const int rq = l >> 2, dq = (l & 3) * 16;
#pragma unroll
    for (int i = 0; i < 2; ++i) {
      uint4 w = *(const uint4*)&ldsT[rq * 72 + dq + 8 * i];
      *(uint4*)&Ob[((size_t)b * S + qw + rq) * Dm + h * 64 + dq + 8 * i] = w;
    }
    __syncthreads();   // all epilogue LDS reads done before next phase's staging
  }
}

// ---------------------------------------------------------------- launch
extern "C" void kernel_launch(void* const* d_in, const int* in_sizes, int n_in,
                              void* d_out, int out_size, void* d_ws, size_t ws_size,
                              hipStream_t stream) {
  const float* query = (const float*)d_in[0];
  const float* key   = (const float*)d_in[1];
  const float* value = (const float*)d_in[2];
  const float* Wq = (const float*)d_in[3]; const float* bq = (const float*)d_in[4];
  const float* Wk = (const float*)d_in[5]; const float* bk = (const float*)d_in[6];
  const float* Wv = (const float*)d_in[7]; const float* bv = (const float*)d_in[8];
  const float* Wo = (const float*)d_in[9]; const float* bo = (const float*)d_in[10];
  float* out = (float*)d_out;

  char* ws = (char*)d_ws;
  const size_t MB = 1024 * 1024;
  bf16* xq  = (bf16*)(ws + 0 * MB);
  bf16* xk  = (bf16*)(ws + 8 * MB);
  bf16* xv  = (bf16*)(ws + 16 * MB);
  bf16* qp  = (bf16*)(ws + 24 * MB);
  bf16* kp  = (bf16*)(ws + 32 * MB);
  bf16* vp  = (bf16*)(ws + 40 * MB);
  bf16* WqT = (bf16*)(ws + 48 * MB);
  bf16* WkT = (bf16*)(ws + 50 * MB);
  bf16* WvT = (bf16*)(ws + 52 * MB);
  bf16* WoT = (bf16*)(ws + 54 * MB);
  bf16* VT   = xq;   // xq consumed by gemm_qkv before vtrans runs
  bf16* attn = xk;   // xk consumed by gemm_qkv before attn runs

  PrepArgs pa;
  pa.x[0] = query; pa.x[1] = key; pa.x[2] = value;
  pa.y[0] = xq; pa.y[1] = xk; pa.y[2] = xv;
  pa.W[0] = Wq; pa.W[1] = Wk; pa.W[2] = Wv; pa.W[3] = Wo;
  pa.WT[0] = WqT; pa.WT[1] = WkT; pa.WT[2] = WvT; pa.WT[3] = WoT;
  prep_kernel<<<10240, 256, 0, stream>>>(pa);

  QKVArgs qa;
  qa.A[0] = xq;  qa.A[1] = xk;  qa.A[2] = xv;
  qa.BT[0] = WqT; qa.BT[1] = WkT; qa.BT[2] = WvT;
  qa.bias[0] = bq; qa.bias[1] = bk; qa.bias[2] = bv;
  qa.out[0] = qp; qa.out[1] = kp; qa.out[2] = vp;
  gemm_qkv_kernel<<<dim3(8, 32, 3), 256, 0, stream>>>(qa);

  vtrans_kernel<<<dim3(32, 32), 256, 0, stream>>>(vp, VT);
  attn_kernel<<<dim3(16, 32), 256, 0, stream>>>(qp, kp, VT, attn);
  gemm_out_kernel<<<dim3(8, 64), 256, 0, stream>>>(attn, WoT, bo, out);
}